// Round 4
// baseline (731.941 us; speedup 1.0000x reference)
//
#include <hip/hip_runtime.h>
#include <math.h>

#define B_TOK 8192
#define D_IN 1024
#define D_OUT 1024
#define N_E 8
#define N_H 128
#define SEL 2048
#define CAND_CAP 4096
#define BAND 2.5e-3f

using bf16x8 = __attribute__((ext_vector_type(8))) short;
using floatx4 = __attribute__((ext_vector_type(4))) float;

__device__ __forceinline__ unsigned short f2bf(float f) {
  unsigned u = __float_as_uint(f);
  u = (u + 0x7FFFu + ((u >> 16) & 1u)) >> 16;
  return (unsigned short)u;
}

__device__ __forceinline__ void async_cp16(const void* g, void* l) {
  __builtin_amdgcn_global_load_lds((__attribute__((address_space(1))) void*)g,
                                   (__attribute__((address_space(3))) void*)l,
                                   16, 0, 0);
}

// order-preserving uint key for signed floats (ascending)
__device__ __forceinline__ unsigned km(float f) {
  unsigned u = __float_as_uint(f);
  return (u & 0x80000000u) ? ~u : (u | 0x80000000u);
}
__device__ __forceinline__ float unkm(unsigned k) {
  unsigned u = (k & 0x80000000u) ? (k & 0x7FFFFFFFu) : ~k;
  return __uint_as_float(u);
}

// block reductions for 1024-thread blocks (16 waves)
__device__ __forceinline__ int bsum_i(int v, volatile int* red, int t) {
  for (int o = 32; o; o >>= 1) v += __shfl_down(v, o);
  __syncthreads();
  if ((t & 63) == 0) red[t >> 6] = v;
  __syncthreads();
  int s = 0;
#pragma unroll
  for (int j = 0; j < 16; ++j) s += red[j];
  return s;
}
__device__ __forceinline__ double bsum_d(double v, volatile double* red, int t) {
  for (int o = 32; o; o >>= 1) v += __shfl_down(v, o);
  __syncthreads();
  if ((t & 63) == 0) red[t >> 6] = v;
  __syncthreads();
  double s = 0.0;
#pragma unroll
  for (int j = 0; j < 16; ++j) s += red[j];
  return s;
}
__device__ __forceinline__ float bmax_f(float v, volatile float* red, int t) {
  for (int o = 32; o; o >>= 1) v = fmaxf(v, __shfl_down(v, o));
  __syncthreads();
  if ((t & 63) == 0) red[t >> 6] = v;
  __syncthreads();
  float s = -3.4e38f;
#pragma unroll
  for (int j = 0; j < 16; ++j) s = fmaxf(s, red[j]);
  return s;
}

// ---------------- cast x -> bf16 ----------------
__global__ __launch_bounds__(256) void k_cast_x(const float* __restrict__ x,
                                                unsigned short* __restrict__ xb) {
  int i = (blockIdx.x * 256 + threadIdx.x) * 8;
  float4 a = *(const float4*)(x + i);
  float4 b = *(const float4*)(x + i + 4);
  ushort4 lo; lo.x = f2bf(a.x); lo.y = f2bf(a.y); lo.z = f2bf(a.z); lo.w = f2bf(a.w);
  ushort4 hi; hi.x = f2bf(b.x); hi.y = f2bf(b.y); hi.z = f2bf(b.z); hi.w = f2bf(b.w);
  *(ushort4*)(xb + i) = lo;
  *(ushort4*)(xb + i + 4) = hi;
}

// ---------------- transpose+cast we -> web[e][o][d] bf16 ----------------
__global__ __launch_bounds__(256) void k_cast_weT(const float* __restrict__ we,
                                                  unsigned short* __restrict__ web) {
  __shared__ float tile[64][68];
  const int e = blockIdx.z;
  const float* wsrc = we + (size_t)e * D_IN * D_OUT;
  unsigned short* wdst = web + (size_t)e * D_OUT * D_IN;
  const int t = threadIdx.x;
  const int r = t >> 4;
  const int c = (t & 15) * 4;
  const int d0 = blockIdx.x * 64, o0 = blockIdx.y * 64;
#pragma unroll
  for (int p = 0; p < 4; ++p) {
    float4 v = *(const float4*)(wsrc + (size_t)(d0 + r + 16 * p) * D_OUT + o0 + c);
    tile[r + 16 * p][c] = v.x; tile[r + 16 * p][c + 1] = v.y;
    tile[r + 16 * p][c + 2] = v.z; tile[r + 16 * p][c + 3] = v.w;
  }
  __syncthreads();
#pragma unroll
  for (int p = 0; p < 4; ++p) {
    int orow = r + 16 * p;
    ushort4 v;
    v.x = f2bf(tile[c + 0][orow]); v.y = f2bf(tile[c + 1][orow]);
    v.z = f2bf(tile[c + 2][orow]); v.w = f2bf(tile[c + 3][orow]);
    *(ushort4*)(wdst + (size_t)(o0 + orow) * D_IN + d0 + c) = v;
  }
}

// ---------------- build Wc[256][1024] bf16 = concat(w1,wg)^T ----------------
__global__ __launch_bounds__(256) void k_cast_wr(const float* __restrict__ w1,
                                                 const float* __restrict__ wg,
                                                 unsigned short* __restrict__ wc) {
  __shared__ float tile[64][68];
  const int t = threadIdx.x;
  const int r = t >> 4;
  const int c = (t & 15) * 4;
  const int k0 = blockIdx.x * 64;
  const int n0 = blockIdx.y * 64;
  const float* src = (n0 < N_H) ? w1 : wg;
  const int nc0 = n0 & (N_H - 1);
#pragma unroll
  for (int p = 0; p < 4; ++p) {
    float4 v = *(const float4*)(src + (size_t)(k0 + r + 16 * p) * N_H + nc0 + c);
    tile[r + 16 * p][c] = v.x; tile[r + 16 * p][c + 1] = v.y;
    tile[r + 16 * p][c + 2] = v.z; tile[r + 16 * p][c + 3] = v.w;
  }
  __syncthreads();
#pragma unroll
  for (int p = 0; p < 4; ++p) {
    int orow = r + 16 * p;
    ushort4 v;
    v.x = f2bf(tile[c + 0][orow]); v.y = f2bf(tile[c + 1][orow]);
    v.z = f2bf(tile[c + 2][orow]); v.w = f2bf(tile[c + 3][orow]);
    *(ushort4*)(wc + (size_t)(n0 + orow) * D_IN + k0 + c) = v;
  }
}

// ---------------- router GEMM: ag[8192][256] = xb @ Wc^T (bf16 MFMA) ----------------
__global__ __launch_bounds__(256) void k_gemm_router(const unsigned short* __restrict__ xb,
                                                     const unsigned short* __restrict__ wc,
                                                     float* __restrict__ ag) {
  __shared__ unsigned short As[128 * 64];
  __shared__ unsigned short Bs[128 * 64];
  const int m0 = blockIdx.x * 128;
  const int bn = blockIdx.y * 128;
  const int t = threadIdx.x;
  const int wave = t >> 6, lane = t & 63;
  const int chunk = lane & 7;
  const unsigned short* aptr[4];
  const unsigned short* bptr[4];
  unsigned short* adst[4];
  unsigned short* bdst[4];
#pragma unroll
  for (int c = 0; c < 4; ++c) {
    int row = c * 32 + wave * 8 + (lane >> 3);
    aptr[c] = xb + (size_t)(m0 + row) * D_IN + chunk * 8;
    bptr[c] = wc + (size_t)(bn + row) * D_IN + chunk * 8;
    adst[c] = As + row * 64 + chunk * 8;
    bdst[c] = Bs + row * 64 + chunk * 8;
  }
  floatx4 acc[4][4] = {};
  const int wm = wave >> 1, wn = wave & 1;
  const int fr = lane & 15, fq = lane >> 4;
  for (int k0 = 0; k0 < D_IN; k0 += 64) {
#pragma unroll
    for (int c = 0; c < 4; ++c) {
      async_cp16(aptr[c] + k0, adst[c]);
      async_cp16(bptr[c] + k0, bdst[c]);
    }
    __syncthreads();
#pragma unroll
    for (int kk = 0; kk < 2; ++kk) {
      bf16x8 af[4], bfr[4];
#pragma unroll
      for (int mt = 0; mt < 4; ++mt)
        af[mt] = *(const bf16x8*)(As + (wm * 64 + mt * 16 + fr) * 64 + kk * 32 + fq * 8);
#pragma unroll
      for (int nt = 0; nt < 4; ++nt)
        bfr[nt] = *(const bf16x8*)(Bs + (wn * 64 + nt * 16 + fr) * 64 + kk * 32 + fq * 8);
#pragma unroll
      for (int mt = 0; mt < 4; ++mt)
#pragma unroll
        for (int nt = 0; nt < 4; ++nt)
          acc[mt][nt] = __builtin_amdgcn_mfma_f32_16x16x32_bf16(af[mt], bfr[nt], acc[mt][nt], 0, 0, 0);
    }
    __syncthreads();
  }
#pragma unroll
  for (int mt = 0; mt < 4; ++mt)
#pragma unroll
    for (int r = 0; r < 4; ++r) {
      int lrow = wm * 64 + mt * 16 + fq * 4 + r;
#pragma unroll
      for (int nt = 0; nt < 4; ++nt) {
        int cc = bn + wn * 64 + nt * 16 + fr;
        ag[(size_t)(m0 + lrow) * 256 + cc] = acc[mt][nt][r];
      }
    }
}

// ---------------- h + logits (approx, fp32) ----------------
__global__ __launch_bounds__(256) void k_h_logits(const float* __restrict__ ag,
                                                  const float* __restrict__ b1,
                                                  const float* __restrict__ bg,
                                                  const float* __restrict__ w2,
                                                  const float* __restrict__ b2,
                                                  float* __restrict__ logits_f) {
  __shared__ float w2s[N_H * N_E];
  const int t = threadIdx.x;
  ((float4*)w2s)[t] = ((const float4*)w2)[t];
  __syncthreads();
  const int token = blockIdx.x * 64 + (t >> 2);
  const int part = t & 3;
  const int p32 = part * 32;
  float acc[8] = {};
  const float* arow = ag + (size_t)token * 256;
#pragma unroll
  for (int k = 0; k < 32; k += 4) {
    float4 av = *(const float4*)(arow + p32 + k);
    float4 gv = *(const float4*)(arow + 128 + p32 + k);
    float4 b1v = *(const float4*)(b1 + p32 + k);
    float4 bgv = *(const float4*)(bg + p32 + k);
    float ha[4];
    ha[0] = fmaxf((av.x + b1v.x) * fmaxf(gv.x + bgv.x, 0.f), 0.f);
    ha[1] = fmaxf((av.y + b1v.y) * fmaxf(gv.y + bgv.y, 0.f), 0.f);
    ha[2] = fmaxf((av.z + b1v.z) * fmaxf(gv.z + bgv.z, 0.f), 0.f);
    ha[3] = fmaxf((av.w + b1v.w) * fmaxf(gv.w + bgv.w, 0.f), 0.f);
#pragma unroll
    for (int j = 0; j < 4; ++j) {
      int kk = p32 + k + j;
#pragma unroll
      for (int e = 0; e < 8; ++e) acc[e] += ha[j] * w2s[kk * N_E + e];
    }
  }
#pragma unroll
  for (int e = 0; e < 8; ++e) {
    acc[e] += __shfl_down(acc[e], 1);
    acc[e] += __shfl_down(acc[e], 2);
  }
  if (part == 0) {
#pragma unroll
    for (int e = 0; e < 8; ++e)
      logits_f[(size_t)token * N_E + e] = acc[e] + b2[e];
  }
}

// ---------------- pass1: approx rank-2048 threshold per expert ----------------
__global__ __launch_bounds__(1024) void k_pass1(const float* __restrict__ logits_f,
                                                float* __restrict__ thrF,
                                                int* __restrict__ gcount) {
  const int e = blockIdx.x;
  const int t = threadIdx.x;
  __shared__ int red[16];
  unsigned kr[8];
#pragma unroll
  for (int i = 0; i < 8; ++i) kr[i] = km(logits_f[(size_t)(t + i * 1024) * N_E + e]);
  unsigned thr = 0;
  for (int bit = 31; bit >= 0; --bit) {
    unsigned trial = thr | (1u << bit);
    int c = 0;
#pragma unroll
    for (int i = 0; i < 8; ++i) c += (kr[i] >= trial) ? 1 : 0;
    c = bsum_i(c, red, t);
    if (c >= SEL) thr = trial;
  }
  if (t == 0) thrF[e] = unkm(thr);
  if (t == 1 && e == 0) gcount[0] = 0;
}

// ---------------- mark: slot init + candidate list ----------------
__global__ __launch_bounds__(256) void k_mark(const float* __restrict__ logits_f,
                                              const float* __restrict__ thrF,
                                              int* __restrict__ slot,
                                              int* __restrict__ clist,
                                              int* __restrict__ gcount) {
  __shared__ float th[8];
  const int t = threadIdx.x;
  if (t < 8) th[t] = thrF[t];
  __syncthreads();
  const int tok = blockIdx.x * 256 + t;
  float4 l0 = *(const float4*)(logits_f + (size_t)tok * N_E);
  float4 l1 = *(const float4*)(logits_f + (size_t)tok * N_E + 4);
  int4 mi = {-1, -1, -1, -1};
  *(int4*)(slot + (size_t)tok * N_E) = mi;
  *(int4*)(slot + (size_t)tok * N_E + 4) = mi;
  bool cand = (fabsf(l0.x - th[0]) <= BAND) | (fabsf(l0.y - th[1]) <= BAND) |
              (fabsf(l0.z - th[2]) <= BAND) | (fabsf(l0.w - th[3]) <= BAND) |
              (fabsf(l1.x - th[4]) <= BAND) | (fabsf(l1.y - th[5]) <= BAND) |
              (fabsf(l1.z - th[6]) <= BAND) | (fabsf(l1.w - th[7]) <= BAND);
  if (cand) {
    int pos = atomicAdd(gcount, 1);
    if (pos < CAND_CAP) clist[pos] = tok;
  }
}

// ---------------- recheck pass A: exact h for candidate tokens (batched, r1 numerics) ----------------
__global__ __launch_bounds__(256) void k_recheck_h(const float* __restrict__ x,
                                                   const float* __restrict__ w1,
                                                   const float* __restrict__ b1,
                                                   const float* __restrict__ wg,
                                                   const float* __restrict__ bg,
                                                   const int* __restrict__ clist,
                                                   const int* __restrict__ gcount,
                                                   float* __restrict__ hc) {
  const int n = min(gcount[0], CAND_CAP);
  const int t = threadIdx.x;
  const int tg = t >> 5;   // 0..7 -> 4 tokens each
  const int og = t & 31;   // 0..31 -> 4 outputs each
  __shared__ float xs[32][36];
  __shared__ float ws1[32][128];
  __shared__ float wsg[32][128];
  __shared__ int tokid[32];

  for (int tile = blockIdx.x; tile * 32 < n; tile += 64) {
    const int base = tile * 32;
    __syncthreads();
    if (t < 32) {
      int c = base + t;
      tokid[t] = (c < n) ? clist[c] : clist[0];
    }
    __syncthreads();
    double d1[4][4] = {}; double dg[4][4] = {};
    for (int k0 = 0; k0 < D_IN; k0 += 32) {
      __syncthreads();
      {
        int r = t >> 3, c = (t & 7) * 4;
        float4 v = *(const float4*)(x + (size_t)tokid[r] * D_IN + k0 + c);
        *(float4*)(&xs[r][c]) = v;
      }
      {
        int r = t >> 5, c = (t & 31) * 4;
#pragma unroll
        for (int p = 0; p < 4; ++p) {
          *(float4*)(&ws1[r + 8 * p][c]) = *(const float4*)(w1 + (size_t)(k0 + r + 8 * p) * N_H + c);
          *(float4*)(&wsg[r + 8 * p][c]) = *(const float4*)(wg + (size_t)(k0 + r + 8 * p) * N_H + c);
        }
      }
      __syncthreads();
      float a1[4][4] = {}; float ag2[4][4] = {};
      for (int k = 0; k < 32; k += 4) {
        float xk[4][4];
#pragma unroll
        for (int i = 0; i < 4; ++i) {
          float4 v = *(const float4*)(&xs[tg * 4 + i][k]);
          xk[i][0] = v.x; xk[i][1] = v.y; xk[i][2] = v.z; xk[i][3] = v.w;
        }
#pragma unroll
        for (int kk = 0; kk < 4; ++kk) {
          float4 w1v = *(const float4*)(&ws1[k + kk][og * 4]);
          float4 wgv = *(const float4*)(&wsg[k + kk][og * 4]);
          float wa1[4] = {w1v.x, w1v.y, w1v.z, w1v.w};
          float wag[4] = {wgv.x, wgv.y, wgv.z, wgv.w};
#pragma unroll
          for (int i = 0; i < 4; ++i) {
#pragma unroll
            for (int j = 0; j < 4; ++j) {
              a1[i][j] += xk[i][kk] * wa1[j];
              ag2[i][j] += xk[i][kk] * wag[j];
            }
          }
        }
      }
#pragma unroll
      for (int i = 0; i < 4; ++i)
#pragma unroll
        for (int j = 0; j < 4; ++j) { d1[i][j] += a1[i][j]; dg[i][j] += ag2[i][j]; }
    }
    float4 b1v = *(const float4*)(b1 + og * 4);
    float4 bgv = *(const float4*)(bg + og * 4);
    float b1a[4] = {b1v.x, b1v.y, b1v.z, b1v.w};
    float bga[4] = {bgv.x, bgv.y, bgv.z, bgv.w};
#pragma unroll
    for (int i = 0; i < 4; ++i) {
      int c = base + tg * 4 + i;
      if (c < n) {
        float hv[4];
#pragma unroll
        for (int j = 0; j < 4; ++j) {
          float a = (float)d1[i][j] + b1a[j];
          float g = (float)dg[i][j] + bga[j];
          g = fmaxf(g, 0.f);
          hv[j] = fmaxf(a * g, 0.f);
        }
        *(float4*)(hc + (size_t)c * N_H + og * 4) = *(float4*)hv;
      }
    }
  }
}

// ---------------- recheck pass B: exact logits (fp64) for candidates ----------------
__global__ __launch_bounds__(256) void k_recheck_logits(const float* __restrict__ hc,
                                                        const float* __restrict__ w2,
                                                        const float* __restrict__ b2,
                                                        const int* __restrict__ clist,
                                                        const int* __restrict__ gcount,
                                                        float* __restrict__ logits_f) {
  const int n = min(gcount[0], CAND_CAP);
  __shared__ float w2s[N_H * N_E];
  const int t = threadIdx.x;
  ((float4*)w2s)[t] = ((const float4*)w2)[t];
  __syncthreads();
  const int part = t & 3;
  const int p32 = part * 32;
  for (int c0 = blockIdx.x * 64; c0 < n; c0 += 32 * 64) {
    const int c = c0 + (t >> 2);
    const int cc = (c < n) ? c : 0;
    double acc[8] = {};
    const float* hrow = hc + (size_t)cc * N_H + p32;
#pragma unroll
    for (int k = 0; k < 32; k += 4) {
      float4 hv = *(const float4*)(hrow + k);
      float ha[4] = {hv.x, hv.y, hv.z, hv.w};
#pragma unroll
      for (int l = 0; l < 4; ++l) {
        int kk = p32 + k + l;
#pragma unroll
        for (int e2 = 0; e2 < 8; ++e2)
          acc[e2] += (double)ha[l] * (double)w2s[kk * N_E + e2];
      }
    }
#pragma unroll
    for (int e2 = 0; e2 < 8; ++e2) {
      acc[e2] += __shfl_down(acc[e2], 1);
      acc[e2] += __shfl_down(acc[e2], 2);
    }
    if (part == 0 && c < n) {
      int tok = clist[c];
#pragma unroll
      for (int e2 = 0; e2 < 8; ++e2)
        logits_f[(size_t)tok * N_E + e2] = (float)(acc[e2] + (double)b2[e2]);
    }
  }
}

// ---------------- final: prob-space top-2048 + reference-matching nws ----------------
__global__ __launch_bounds__(1024) void k_final(const float* __restrict__ logits_f,
                                                int* __restrict__ ib, float* __restrict__ nws,
                                                int* __restrict__ slot) {
  const int e = blockIdx.x;
  const int t = threadIdx.x;
  __shared__ int red[16];
  __shared__ double redd[16];
  __shared__ float redf[16];
  __shared__ int s_cnt;
  float lv[8];
#pragma unroll
  for (int i = 0; i < 8; ++i) lv[i] = logits_f[(size_t)(t + i * 1024) * N_E + e];

  float m = -3.4e38f;
#pragma unroll
  for (int i = 0; i < 8; ++i) m = fmaxf(m, lv[i]);
  m = bmax_f(m, redf, t);

  double ev[8];
  double s = 0.0;
#pragma unroll
  for (int i = 0; i < 8; ++i) { ev[i] = exp((double)lv[i] - (double)m); s += ev[i]; }
  s = bsum_d(s, redd, t);

  float pv[8];
  unsigned kr[8];
#pragma unroll
  for (int i = 0; i < 8; ++i) {
    pv[i] = (float)(ev[i] / s);
    kr[i] = __float_as_uint(pv[i]);
  }

  unsigned thr = 0;
  for (int bit = 31; bit >= 0; --bit) {
    unsigned trial = thr | (1u << bit);
    int c = 0;
#pragma unroll
    for (int i = 0; i < 8; ++i) c += (kr[i] >= trial) ? 1 : 0;
    c = bsum_i(c, red, t);
    if (c >= SEL) thr = trial;
  }
  int c1 = 0;
#pragma unroll
  for (int i = 0; i < 8; ++i) c1 += (kr[i] > thr) ? 1 : 0;
  c1 = bsum_i(c1, red, t);
  const int need = SEL - c1;
  int cut = 0;
  for (int bit = 12; bit >= 0; --bit) {
    int trial = cut | (1 << bit);
    int c = 0;
#pragma unroll
    for (int i = 0; i < 8; ++i) c += (kr[i] == thr && (t + i * 1024) < trial) ? 1 : 0;
    c = bsum_i(c, red, t);
    if (c < need) cut = trial;
  }

  float pm = 0.f;
#pragma unroll
  for (int i = 0; i < 8; ++i) pm = fmaxf(pm, pv[i]);
  pm = bmax_f(pm, redf, t);

  double ss = 0.0;
#pragma unroll
  for (int i = 0; i < 8; ++i) {
    int idx = t + i * 1024;
    bool sel = (kr[i] > thr) || (kr[i] == thr && idx <= cut);
    if (sel) ss += exp((double)pv[i] - (double)pm);
  }
  ss = bsum_d(ss, redd, t);

  if (t == 0) s_cnt = 0;
  __syncthreads();
  for (int i = 0; i < 8; ++i) {
    int idx = t + i * 1024;
    bool sel = (kr[i] > thr) || (kr[i] == thr && idx <= cut);
    if (sel) {
      int pos = atomicAdd(&s_cnt, 1);
      if (pos < SEL) {
        ib[e * SEL + pos] = idx;
        nws[e * SEL + pos] = (float)(exp((double)pv[i] - (double)pm) / ss);
        slot[(size_t)idx * N_E + e] = pos;
      }
    }
  }
}

// ---------------- expert GEMM ----------------
__global__ __launch_bounds__(256) void k_expert_gemm(const unsigned short* __restrict__ xb,
                                                     const unsigned short* __restrict__ web,
                                                     const float* __restrict__ be,
                                                     const int* __restrict__ ib,
                                                     const float* __restrict__ nws,
                                                     float* __restrict__ eo) {
  __shared__ unsigned short As[128 * 64];
  __shared__ unsigned short Bs[128 * 64];
  __shared__ int rowidx[128];
  __shared__ float nwss[128];
  const int e = blockIdx.z;
  const int bm = blockIdx.x * 128;
  const int bn = blockIdx.y * 128;
  const int t = threadIdx.x;
  const int wave = t >> 6, lane = t & 63;
  if (t < 128) {
    rowidx[t] = ib[e * SEL + bm + t];
    nwss[t] = nws[e * SEL + bm + t];
  }
  __syncthreads();
  const unsigned short* wbase = web + (size_t)e * D_IN * D_OUT;
  const int chunk = lane & 7;
  const unsigned short* aptr[4];
  const unsigned short* bptr[4];
  unsigned short* adst[4];
  unsigned short* bdst[4];
#pragma unroll
  for (int c = 0; c < 4; ++c) {
    int row = c * 32 + wave * 8 + (lane >> 3);
    aptr[c] = xb + (size_t)rowidx[row] * D_IN + chunk * 8;
    bptr[c] = wbase + (size_t)(bn + row) * D_IN + chunk * 8;
    adst[c] = As + row * 64 + chunk * 8;
    bdst[c] = Bs + row * 64 + chunk * 8;
  }
  floatx4 acc[4][4] = {};
  const int wm = wave >> 1, wn = wave & 1;
  const int fr = lane & 15, fq = lane >> 4;
  for (int k0 = 0; k0 < D_IN; k0 += 64) {
#pragma unroll
    for (int c = 0; c < 4; ++c) {
      async_cp16(aptr[c] + k0, adst[c]);
      async_cp16(bptr[c] + k0, bdst[c]);
    }
    __syncthreads();
#pragma unroll
    for (int kk = 0; kk < 2; ++kk) {
      bf16x8 af[4], bfr[4];
#pragma unroll
      for (int mt = 0; mt < 4; ++mt)
        af[mt] = *(const bf16x8*)(As + (wm * 64 + mt * 16 + fr) * 64 + kk * 32 + fq * 8);
#pragma unroll
      for (int nt = 0; nt < 4; ++nt)
        bfr[nt] = *(const bf16x8*)(Bs + (wn * 64 + nt * 16 + fr) * 64 + kk * 32 + fq * 8);
#pragma unroll
      for (int mt = 0; mt < 4; ++mt)
#pragma unroll
        for (int nt = 0; nt < 4; ++nt)
          acc[mt][nt] = __builtin_amdgcn_mfma_f32_16x16x32_bf16(af[mt], bfr[nt], acc[mt][nt], 0, 0, 0);
    }
    __syncthreads();
  }
  float bev[4];
#pragma unroll
  for (int nt = 0; nt < 4; ++nt) bev[nt] = be[e * D_OUT + bn + wn * 64 + nt * 16 + fr];
#pragma unroll
  for (int mt = 0; mt < 4; ++mt) {
#pragma unroll
    for (int r = 0; r < 4; ++r) {
      int lrow = wm * 64 + mt * 16 + fq * 4 + r;
      float nw = nwss[lrow];
      size_t rbase = ((size_t)e * SEL + bm + lrow) * D_OUT;
#pragma unroll
      for (int nt = 0; nt < 4; ++nt) {
        int cc = bn + wn * 64 + nt * 16 + fr;
        eo[rbase + cc] = (acc[mt][nt][r] + bev[nt]) * nw;
      }
    }
  }
}

// ---------------- combine ----------------
__global__ __launch_bounds__(256) void k_combine(const float* __restrict__ eo,
                                                 const int* __restrict__ slot,
                                                 float* __restrict__ out) {
  const int b = blockIdx.x;
  const int t = threadIdx.x;
  __shared__ int ss[8];
  if (t < 8) ss[t] = slot[(size_t)b * N_E + t];
  __syncthreads();
  const int d0 = t * 4;
  float vx[8], vy[8], vz[8], vw[8];
  float tx = 0.f, ty = 0.f, tz = 0.f, tw = 0.f;
#pragma unroll
  for (int e = 0; e < 8; ++e) {
    int k = ss[e];
    if (k >= 0) {
      float4 v = *(const float4*)(eo + ((size_t)e * SEL + k) * D_OUT + d0);
      vx[e] = v.x; vy[e] = v.y; vz[e] = v.z; vw[e] = v.w;
      tx += v.x; ty += v.y; tz += v.z; tw += v.w;
    } else {
      vx[e] = 0.f; vy[e] = 0.f; vz[e] = 0.f; vw[e] = 0.f;
    }
  }
#pragma unroll
  for (int e = 0; e < 8; ++e) {
    float4 o;
    o.x = tx + vx[e]; o.y = ty + vy[e]; o.z = tz + vz[e]; o.w = tw + vw[e];
    *(float4*)(out + (size_t)b * (N_E * D_OUT) + e * D_OUT + d0) = o;
  }
}

extern "C" void kernel_launch(void* const* d_in, const int* in_sizes, int n_in,
                              void* d_out, int out_size, void* d_ws, size_t ws_size,
                              hipStream_t stream) {
  const float* x  = (const float*)d_in[0];
  const float* w1 = (const float*)d_in[1];
  const float* b1 = (const float*)d_in[2];
  const float* wg = (const float*)d_in[3];
  const float* bg = (const float*)d_in[4];
  const float* w2 = (const float*)d_in[5];
  const float* b2 = (const float*)d_in[6];
  const float* we = (const float*)d_in[7];
  const float* be = (const float*)d_in[8];
  float* out = (float*)d_out;

  char* ws = (char*)d_ws;
  size_t off = 0;
  auto alloc = [&](size_t bytes) -> void* {
    void* p = ws + off;
    off += (bytes + 255) & ~(size_t)255;
    return p;
  };
  unsigned short* xb   = (unsigned short*)alloc((size_t)B_TOK * D_IN * 2);
  unsigned short* web  = (unsigned short*)alloc((size_t)N_E * D_IN * D_OUT * 2);
  unsigned short* wc   = (unsigned short*)alloc((size_t)256 * D_IN * 2);
  float* eo       = (float*)alloc((size_t)N_E * SEL * D_OUT * 4);
  float* ag       = (float*)alloc((size_t)B_TOK * 256 * 4);
  float* logits_f = (float*)alloc((size_t)B_TOK * N_E * 4);
  float* hc       = (float*)alloc((size_t)CAND_CAP * N_H * 4);
  int* ibuf       = (int*)alloc((size_t)N_E * SEL * 4);
  float* nws      = (float*)alloc((size_t)N_E * SEL * 4);
  int* slot       = (int*)alloc((size_t)B_TOK * N_E * 4);
  float* thrF     = (float*)alloc(8 * 4);
  int* clist      = (int*)alloc((size_t)CAND_CAP * 4);
  int* gcount     = (int*)alloc(4);
  if (off > ws_size) return;

  hipLaunchKernelGGL(k_cast_x, dim3(B_TOK * D_IN / (256 * 8)), dim3(256), 0, stream, x, xb);
  hipLaunchKernelGGL(k_cast_weT, dim3(16, 16, N_E), dim3(256), 0, stream, we, web);
  hipLaunchKernelGGL(k_cast_wr, dim3(16, 4), dim3(256), 0, stream, w1, wg, wc);
  hipLaunchKernelGGL(k_gemm_router, dim3(B_TOK / 128, 2), dim3(256), 0, stream, xb, wc, ag);
  hipLaunchKernelGGL(k_h_logits, dim3(B_TOK / 64), dim3(256), 0, stream, ag, b1, bg, w2, b2, logits_f);
  hipLaunchKernelGGL(k_pass1, dim3(N_E), dim3(1024), 0, stream, logits_f, thrF, gcount);
  hipLaunchKernelGGL(k_mark, dim3(B_TOK / 256), dim3(256), 0, stream, logits_f, thrF, slot, clist, gcount);
  hipLaunchKernelGGL(k_recheck_h, dim3(64), dim3(256), 0, stream, x, w1, b1, wg, bg, clist, gcount, hc);
  hipLaunchKernelGGL(k_recheck_logits, dim3(32), dim3(256), 0, stream, hc, w2, b2, clist, gcount, logits_f);
  hipLaunchKernelGGL(k_final, dim3(N_E), dim3(1024), 0, stream, logits_f, ibuf, nws, slot);
  hipLaunchKernelGGL(k_expert_gemm, dim3(SEL / 128, D_OUT / 128, N_E), dim3(256), 0, stream,
                     xb, web, be, ibuf, nws, eo);
  hipLaunchKernelGGL(k_combine, dim3(B_TOK), dim3(256), 0, stream, eo, slot, out);
}

// Round 5
// 603.504 us; speedup vs baseline: 1.2128x; 1.2128x over previous
//
#include <hip/hip_runtime.h>
#include <math.h>

#define B_TOK 8192
#define D_IN 1024
#define D_OUT 1024
#define N_E 8
#define N_H 128
#define SEL 2048
#define CAND_CAP 4096
#define BAND 2.5e-3f

using bf16x8 = __attribute__((ext_vector_type(8))) short;
using floatx4 = __attribute__((ext_vector_type(4))) float;

__device__ __forceinline__ unsigned short f2bf(float f) {
  unsigned u = __float_as_uint(f);
  u = (u + 0x7FFFu + ((u >> 16) & 1u)) >> 16;
  return (unsigned short)u;
}

__device__ __forceinline__ void async_cp16(const void* g, void* l) {
  __builtin_amdgcn_global_load_lds((__attribute__((address_space(1))) void*)g,
                                   (__attribute__((address_space(3))) void*)l,
                                   16, 0, 0);
}

// order-preserving uint key for signed floats (ascending)
__device__ __forceinline__ unsigned km(float f) {
  unsigned u = __float_as_uint(f);
  return (u & 0x80000000u) ? ~u : (u | 0x80000000u);
}
__device__ __forceinline__ float unkm(unsigned k) {
  unsigned u = (k & 0x80000000u) ? (k & 0x7FFFFFFFu) : ~k;
  return __uint_as_float(u);
}

// block reductions for 1024-thread blocks (16 waves)
__device__ __forceinline__ int bsum_i(int v, volatile int* red, int t) {
  for (int o = 32; o; o >>= 1) v += __shfl_down(v, o);
  __syncthreads();
  if ((t & 63) == 0) red[t >> 6] = v;
  __syncthreads();
  int s = 0;
#pragma unroll
  for (int j = 0; j < 16; ++j) s += red[j];
  return s;
}
__device__ __forceinline__ double bsum_d(double v, volatile double* red, int t) {
  for (int o = 32; o; o >>= 1) v += __shfl_down(v, o);
  __syncthreads();
  if ((t & 63) == 0) red[t >> 6] = v;
  __syncthreads();
  double s = 0.0;
#pragma unroll
  for (int j = 0; j < 16; ++j) s += red[j];
  return s;
}
__device__ __forceinline__ float bmax_f(float v, volatile float* red, int t) {
  for (int o = 32; o; o >>= 1) v = fmaxf(v, __shfl_down(v, o));
  __syncthreads();
  if ((t & 63) == 0) red[t >> 6] = v;
  __syncthreads();
  float s = -3.4e38f;
#pragma unroll
  for (int j = 0; j < 16; ++j) s = fmaxf(s, red[j]);
  return s;
}

// ---------------- cast x -> bf16 ----------------
__global__ __launch_bounds__(256) void k_cast_x(const float* __restrict__ x,
                                                unsigned short* __restrict__ xb) {
  int i = (blockIdx.x * 256 + threadIdx.x) * 8;
  float4 a = *(const float4*)(x + i);
  float4 b = *(const float4*)(x + i + 4);
  ushort4 lo; lo.x = f2bf(a.x); lo.y = f2bf(a.y); lo.z = f2bf(a.z); lo.w = f2bf(a.w);
  ushort4 hi; hi.x = f2bf(b.x); hi.y = f2bf(b.y); hi.z = f2bf(b.z); hi.w = f2bf(b.w);
  *(ushort4*)(xb + i) = lo;
  *(ushort4*)(xb + i + 4) = hi;
}

// ---------------- transpose+cast we -> web[e][o][d] bf16 ----------------
__global__ __launch_bounds__(256) void k_cast_weT(const float* __restrict__ we,
                                                  unsigned short* __restrict__ web) {
  __shared__ float tile[64][68];
  const int e = blockIdx.z;
  const float* wsrc = we + (size_t)e * D_IN * D_OUT;
  unsigned short* wdst = web + (size_t)e * D_OUT * D_IN;
  const int t = threadIdx.x;
  const int r = t >> 4;
  const int c = (t & 15) * 4;
  const int d0 = blockIdx.x * 64, o0 = blockIdx.y * 64;
#pragma unroll
  for (int p = 0; p < 4; ++p) {
    float4 v = *(const float4*)(wsrc + (size_t)(d0 + r + 16 * p) * D_OUT + o0 + c);
    tile[r + 16 * p][c] = v.x; tile[r + 16 * p][c + 1] = v.y;
    tile[r + 16 * p][c + 2] = v.z; tile[r + 16 * p][c + 3] = v.w;
  }
  __syncthreads();
#pragma unroll
  for (int p = 0; p < 4; ++p) {
    int orow = r + 16 * p;
    ushort4 v;
    v.x = f2bf(tile[c + 0][orow]); v.y = f2bf(tile[c + 1][orow]);
    v.z = f2bf(tile[c + 2][orow]); v.w = f2bf(tile[c + 3][orow]);
    *(ushort4*)(wdst + (size_t)(o0 + orow) * D_IN + d0 + c) = v;
  }
}

// ---------------- build Wc[256][1024] bf16 = concat(w1,wg)^T ----------------
__global__ __launch_bounds__(256) void k_cast_wr(const float* __restrict__ w1,
                                                 const float* __restrict__ wg,
                                                 unsigned short* __restrict__ wc) {
  __shared__ float tile[64][68];
  const int t = threadIdx.x;
  const int r = t >> 4;
  const int c = (t & 15) * 4;
  const int k0 = blockIdx.x * 64;
  const int n0 = blockIdx.y * 64;
  const float* src = (n0 < N_H) ? w1 : wg;
  const int nc0 = n0 & (N_H - 1);
#pragma unroll
  for (int p = 0; p < 4; ++p) {
    float4 v = *(const float4*)(src + (size_t)(k0 + r + 16 * p) * N_H + nc0 + c);
    tile[r + 16 * p][c] = v.x; tile[r + 16 * p][c + 1] = v.y;
    tile[r + 16 * p][c + 2] = v.z; tile[r + 16 * p][c + 3] = v.w;
  }
  __syncthreads();
#pragma unroll
  for (int p = 0; p < 4; ++p) {
    int orow = r + 16 * p;
    ushort4 v;
    v.x = f2bf(tile[c + 0][orow]); v.y = f2bf(tile[c + 1][orow]);
    v.z = f2bf(tile[c + 2][orow]); v.w = f2bf(tile[c + 3][orow]);
    *(ushort4*)(wc + (size_t)(n0 + orow) * D_IN + k0 + c) = v;
  }
}

// ---------------- router GEMM: ag[8192][256] = xb @ Wc^T (bf16 MFMA) ----------------
__global__ __launch_bounds__(256) void k_gemm_router(const unsigned short* __restrict__ xb,
                                                     const unsigned short* __restrict__ wc,
                                                     float* __restrict__ ag) {
  __shared__ unsigned short As[128 * 64];
  __shared__ unsigned short Bs[128 * 64];
  const int m0 = blockIdx.x * 128;
  const int bn = blockIdx.y * 128;
  const int t = threadIdx.x;
  const int wave = t >> 6, lane = t & 63;
  const int chunk = lane & 7;
  const unsigned short* aptr[4];
  const unsigned short* bptr[4];
  unsigned short* adst[4];
  unsigned short* bdst[4];
#pragma unroll
  for (int c = 0; c < 4; ++c) {
    int row = c * 32 + wave * 8 + (lane >> 3);
    aptr[c] = xb + (size_t)(m0 + row) * D_IN + chunk * 8;
    bptr[c] = wc + (size_t)(bn + row) * D_IN + chunk * 8;
    adst[c] = As + row * 64 + chunk * 8;
    bdst[c] = Bs + row * 64 + chunk * 8;
  }
  floatx4 acc[4][4] = {};
  const int wm = wave >> 1, wn = wave & 1;
  const int fr = lane & 15, fq = lane >> 4;
  for (int k0 = 0; k0 < D_IN; k0 += 64) {
#pragma unroll
    for (int c = 0; c < 4; ++c) {
      async_cp16(aptr[c] + k0, adst[c]);
      async_cp16(bptr[c] + k0, bdst[c]);
    }
    __syncthreads();
#pragma unroll
    for (int kk = 0; kk < 2; ++kk) {
      bf16x8 af[4], bfr[4];
#pragma unroll
      for (int mt = 0; mt < 4; ++mt)
        af[mt] = *(const bf16x8*)(As + (wm * 64 + mt * 16 + fr) * 64 + kk * 32 + fq * 8);
#pragma unroll
      for (int nt = 0; nt < 4; ++nt)
        bfr[nt] = *(const bf16x8*)(Bs + (wn * 64 + nt * 16 + fr) * 64 + kk * 32 + fq * 8);
#pragma unroll
      for (int mt = 0; mt < 4; ++mt)
#pragma unroll
        for (int nt = 0; nt < 4; ++nt)
          acc[mt][nt] = __builtin_amdgcn_mfma_f32_16x16x32_bf16(af[mt], bfr[nt], acc[mt][nt], 0, 0, 0);
    }
    __syncthreads();
  }
#pragma unroll
  for (int mt = 0; mt < 4; ++mt)
#pragma unroll
    for (int r = 0; r < 4; ++r) {
      int lrow = wm * 64 + mt * 16 + fq * 4 + r;
#pragma unroll
      for (int nt = 0; nt < 4; ++nt) {
        int cc = bn + wn * 64 + nt * 16 + fr;
        ag[(size_t)(m0 + lrow) * 256 + cc] = acc[mt][nt][r];
      }
    }
}

// ---------------- h + logits (approx, fp32) ----------------
__global__ __launch_bounds__(256) void k_h_logits(const float* __restrict__ ag,
                                                  const float* __restrict__ b1,
                                                  const float* __restrict__ bg,
                                                  const float* __restrict__ w2,
                                                  const float* __restrict__ b2,
                                                  float* __restrict__ logits_f) {
  __shared__ float w2s[N_H * N_E];
  const int t = threadIdx.x;
  ((float4*)w2s)[t] = ((const float4*)w2)[t];
  __syncthreads();
  const int token = blockIdx.x * 64 + (t >> 2);
  const int part = t & 3;
  const int p32 = part * 32;
  float acc[8] = {};
  const float* arow = ag + (size_t)token * 256;
#pragma unroll
  for (int k = 0; k < 32; k += 4) {
    float4 av = *(const float4*)(arow + p32 + k);
    float4 gv = *(const float4*)(arow + 128 + p32 + k);
    float4 b1v = *(const float4*)(b1 + p32 + k);
    float4 bgv = *(const float4*)(bg + p32 + k);
    float ha[4];
    ha[0] = fmaxf((av.x + b1v.x) * fmaxf(gv.x + bgv.x, 0.f), 0.f);
    ha[1] = fmaxf((av.y + b1v.y) * fmaxf(gv.y + bgv.y, 0.f), 0.f);
    ha[2] = fmaxf((av.z + b1v.z) * fmaxf(gv.z + bgv.z, 0.f), 0.f);
    ha[3] = fmaxf((av.w + b1v.w) * fmaxf(gv.w + bgv.w, 0.f), 0.f);
#pragma unroll
    for (int j = 0; j < 4; ++j) {
      int kk = p32 + k + j;
#pragma unroll
      for (int e = 0; e < 8; ++e) acc[e] += ha[j] * w2s[kk * N_E + e];
    }
  }
#pragma unroll
  for (int e = 0; e < 8; ++e) {
    acc[e] += __shfl_down(acc[e], 1);
    acc[e] += __shfl_down(acc[e], 2);
  }
  if (part == 0) {
#pragma unroll
    for (int e = 0; e < 8; ++e)
      logits_f[(size_t)token * N_E + e] = acc[e] + b2[e];
  }
}

// ---------------- pass1: approx rank-2048 threshold per expert ----------------
__global__ __launch_bounds__(1024) void k_pass1(const float* __restrict__ logits_f,
                                                float* __restrict__ thrF,
                                                int* __restrict__ gcount) {
  const int e = blockIdx.x;
  const int t = threadIdx.x;
  __shared__ int red[16];
  unsigned kr[8];
#pragma unroll
  for (int i = 0; i < 8; ++i) kr[i] = km(logits_f[(size_t)(t + i * 1024) * N_E + e]);
  unsigned thr = 0;
  for (int bit = 31; bit >= 0; --bit) {
    unsigned trial = thr | (1u << bit);
    int c = 0;
#pragma unroll
    for (int i = 0; i < 8; ++i) c += (kr[i] >= trial) ? 1 : 0;
    c = bsum_i(c, red, t);
    if (c >= SEL) thr = trial;
  }
  if (t == 0) thrF[e] = unkm(thr);
  if (t == 1 && e == 0) gcount[0] = 0;
}

// ---------------- mark: slot init + candidate list ----------------
__global__ __launch_bounds__(256) void k_mark(const float* __restrict__ logits_f,
                                              const float* __restrict__ thrF,
                                              int* __restrict__ slot,
                                              int* __restrict__ clist,
                                              int* __restrict__ gcount) {
  __shared__ float th[8];
  const int t = threadIdx.x;
  if (t < 8) th[t] = thrF[t];
  __syncthreads();
  const int tok = blockIdx.x * 256 + t;
  float4 l0 = *(const float4*)(logits_f + (size_t)tok * N_E);
  float4 l1 = *(const float4*)(logits_f + (size_t)tok * N_E + 4);
  int4 mi = {-1, -1, -1, -1};
  *(int4*)(slot + (size_t)tok * N_E) = mi;
  *(int4*)(slot + (size_t)tok * N_E + 4) = mi;
  bool cand = (fabsf(l0.x - th[0]) <= BAND) | (fabsf(l0.y - th[1]) <= BAND) |
              (fabsf(l0.z - th[2]) <= BAND) | (fabsf(l0.w - th[3]) <= BAND) |
              (fabsf(l1.x - th[4]) <= BAND) | (fabsf(l1.y - th[5]) <= BAND) |
              (fabsf(l1.z - th[6]) <= BAND) | (fabsf(l1.w - th[7]) <= BAND);
  if (cand) {
    int pos = atomicAdd(gcount, 1);
    if (pos < CAND_CAP) clist[pos] = tok;
  }
}

// ---------------- recheck A: split-k partial sums (exact fp32-chunk/fp64, r1 numerics) ----------------
// grid (CAND_CAP/32, 8): block = (32-token tile, 128-wide k slice). Full-GPU occupancy
// vs r4's 63-block version (measured 170us @ 1.6% occupancy).
__global__ __launch_bounds__(256) void k_recheck_h_part(const float* __restrict__ x,
                                                        const float* __restrict__ w1,
                                                        const float* __restrict__ wg,
                                                        const int* __restrict__ clist,
                                                        const int* __restrict__ gcount,
                                                        float* __restrict__ p1,
                                                        float* __restrict__ pg) {
  const int n = min(gcount[0], CAND_CAP);
  const int tile = blockIdx.x;
  if (n == 0 || tile * 32 >= n) return;
  const int kq = blockIdx.y;
  const int base = tile * 32;
  const int t = threadIdx.x;
  const int tg = t >> 5;   // 0..7 -> 4 tokens each
  const int og = t & 31;   // 0..31 -> 4 outputs each
  __shared__ float xs[32][36];
  __shared__ float ws1[32][128];
  __shared__ float wsg[32][128];
  __shared__ int tokid[32];
  if (t < 32) {
    int c = base + t;
    tokid[t] = (c < n) ? clist[c] : clist[0];
  }
  __syncthreads();
  double d1[4][4] = {}; double dg[4][4] = {};
  const int kbeg = kq * 128;
  for (int k0 = kbeg; k0 < kbeg + 128; k0 += 32) {
    __syncthreads();
    {
      int r = t >> 3, c = (t & 7) * 4;
      float4 v = *(const float4*)(x + (size_t)tokid[r] * D_IN + k0 + c);
      *(float4*)(&xs[r][c]) = v;
    }
    {
      int r = t >> 5, c = (t & 31) * 4;
#pragma unroll
      for (int p = 0; p < 4; ++p) {
        *(float4*)(&ws1[r + 8 * p][c]) = *(const float4*)(w1 + (size_t)(k0 + r + 8 * p) * N_H + c);
        *(float4*)(&wsg[r + 8 * p][c]) = *(const float4*)(wg + (size_t)(k0 + r + 8 * p) * N_H + c);
      }
    }
    __syncthreads();
    float a1[4][4] = {}; float ag2[4][4] = {};
    for (int k = 0; k < 32; k += 4) {
      float xk[4][4];
#pragma unroll
      for (int i = 0; i < 4; ++i) {
        float4 v = *(const float4*)(&xs[tg * 4 + i][k]);
        xk[i][0] = v.x; xk[i][1] = v.y; xk[i][2] = v.z; xk[i][3] = v.w;
      }
#pragma unroll
      for (int kk = 0; kk < 4; ++kk) {
        float4 w1v = *(const float4*)(&ws1[k + kk][og * 4]);
        float4 wgv = *(const float4*)(&wsg[k + kk][og * 4]);
        float wa1[4] = {w1v.x, w1v.y, w1v.z, w1v.w};
        float wag[4] = {wgv.x, wgv.y, wgv.z, wgv.w};
#pragma unroll
        for (int i = 0; i < 4; ++i) {
#pragma unroll
          for (int j = 0; j < 4; ++j) {
            a1[i][j] += xk[i][kk] * wa1[j];
            ag2[i][j] += xk[i][kk] * wag[j];
          }
        }
      }
    }
#pragma unroll
    for (int i = 0; i < 4; ++i)
#pragma unroll
      for (int j = 0; j < 4; ++j) { d1[i][j] += a1[i][j]; dg[i][j] += ag2[i][j]; }
  }
  const size_t kqoff = (size_t)kq * (CAND_CAP * (size_t)N_H);
#pragma unroll
  for (int i = 0; i < 4; ++i) {
    int c = base + tg * 4 + i;
    if (c < n) {
      float4 v1, vg;
      v1.x = (float)d1[i][0]; v1.y = (float)d1[i][1]; v1.z = (float)d1[i][2]; v1.w = (float)d1[i][3];
      vg.x = (float)dg[i][0]; vg.y = (float)dg[i][1]; vg.z = (float)dg[i][2]; vg.w = (float)dg[i][3];
      *(float4*)(p1 + kqoff + (size_t)c * N_H + og * 4) = v1;
      *(float4*)(pg + kqoff + (size_t)c * N_H + og * 4) = vg;
    }
  }
}

// ---------------- recheck B: reduce partials (fixed kq order, fp64) + GLU gate -> hc ----------------
__global__ __launch_bounds__(256) void k_recheck_gate(const float* __restrict__ p1,
                                                      const float* __restrict__ pg,
                                                      const float* __restrict__ b1,
                                                      const float* __restrict__ bg,
                                                      const int* __restrict__ gcount,
                                                      float* __restrict__ hc) {
  const int n = min(gcount[0], CAND_CAP);
  const int idx = blockIdx.x * 256 + threadIdx.x;  // over CAND_CAP*32 o4-groups
  const int c = idx >> 5;
  if (c >= n) return;
  const int o4 = (idx & 31) * 4;
  double a[4] = {}, g[4] = {};
#pragma unroll
  for (int kq = 0; kq < 8; ++kq) {
    const size_t kqoff = (size_t)kq * (CAND_CAP * (size_t)N_H);
    float4 v1 = *(const float4*)(p1 + kqoff + (size_t)c * N_H + o4);
    float4 vg = *(const float4*)(pg + kqoff + (size_t)c * N_H + o4);
    a[0] += v1.x; a[1] += v1.y; a[2] += v1.z; a[3] += v1.w;
    g[0] += vg.x; g[1] += vg.y; g[2] += vg.z; g[3] += vg.w;
  }
  float4 b1v = *(const float4*)(b1 + o4);
  float4 bgv = *(const float4*)(bg + o4);
  float b1a[4] = {b1v.x, b1v.y, b1v.z, b1v.w};
  float bga[4] = {bgv.x, bgv.y, bgv.z, bgv.w};
  float hv[4];
#pragma unroll
  for (int j = 0; j < 4; ++j) {
    float aa = (float)a[j] + b1a[j];
    float gg = (float)g[j] + bga[j];
    gg = fmaxf(gg, 0.f);
    hv[j] = fmaxf(aa * gg, 0.f);
  }
  *(float4*)(hc + (size_t)c * N_H + o4) = *(float4*)hv;
}

// ---------------- recheck C: exact logits (fp64) for candidates ----------------
__global__ __launch_bounds__(256) void k_recheck_logits(const float* __restrict__ hc,
                                                        const float* __restrict__ w2,
                                                        const float* __restrict__ b2,
                                                        const int* __restrict__ clist,
                                                        const int* __restrict__ gcount,
                                                        float* __restrict__ logits_f) {
  const int n = min(gcount[0], CAND_CAP);
  __shared__ float w2s[N_H * N_E];
  const int t = threadIdx.x;
  ((float4*)w2s)[t] = ((const float4*)w2)[t];
  __syncthreads();
  const int part = t & 3;
  const int p32 = part * 32;
  for (int c0 = blockIdx.x * 64; c0 < n; c0 += 64 * 64) {
    const int c = c0 + (t >> 2);
    const int cc = (c < n) ? c : 0;
    double acc[8] = {};
    const float* hrow = hc + (size_t)cc * N_H + p32;
#pragma unroll
    for (int k = 0; k < 32; k += 4) {
      float4 hv = *(const float4*)(hrow + k);
      float ha[4] = {hv.x, hv.y, hv.z, hv.w};
#pragma unroll
      for (int l = 0; l < 4; ++l) {
        int kk = p32 + k + l;
#pragma unroll
        for (int e2 = 0; e2 < 8; ++e2)
          acc[e2] += (double)ha[l] * (double)w2s[kk * N_E + e2];
      }
    }
#pragma unroll
    for (int e2 = 0; e2 < 8; ++e2) {
      acc[e2] += __shfl_down(acc[e2], 1);
      acc[e2] += __shfl_down(acc[e2], 2);
    }
    if (part == 0 && c < n) {
      int tok = clist[c];
#pragma unroll
      for (int e2 = 0; e2 < 8; ++e2)
        logits_f[(size_t)tok * N_E + e2] = (float)(acc[e2] + (double)b2[e2]);
    }
  }
}

// ---------------- final: prob-space top-2048 + reference-matching nws ----------------
__global__ __launch_bounds__(1024) void k_final(const float* __restrict__ logits_f,
                                                int* __restrict__ ib, float* __restrict__ nws,
                                                int* __restrict__ slot) {
  const int e = blockIdx.x;
  const int t = threadIdx.x;
  __shared__ int red[16];
  __shared__ double redd[16];
  __shared__ float redf[16];
  __shared__ int s_cnt;
  float lv[8];
#pragma unroll
  for (int i = 0; i < 8; ++i) lv[i] = logits_f[(size_t)(t + i * 1024) * N_E + e];

  float m = -3.4e38f;
#pragma unroll
  for (int i = 0; i < 8; ++i) m = fmaxf(m, lv[i]);
  m = bmax_f(m, redf, t);

  double ev[8];
  double s = 0.0;
#pragma unroll
  for (int i = 0; i < 8; ++i) { ev[i] = exp((double)lv[i] - (double)m); s += ev[i]; }
  s = bsum_d(s, redd, t);

  float pv[8];
  unsigned kr[8];
#pragma unroll
  for (int i = 0; i < 8; ++i) {
    pv[i] = (float)(ev[i] / s);
    kr[i] = __float_as_uint(pv[i]);
  }

  unsigned thr = 0;
  for (int bit = 31; bit >= 0; --bit) {
    unsigned trial = thr | (1u << bit);
    int c = 0;
#pragma unroll
    for (int i = 0; i < 8; ++i) c += (kr[i] >= trial) ? 1 : 0;
    c = bsum_i(c, red, t);
    if (c >= SEL) thr = trial;
  }
  int c1 = 0;
#pragma unroll
  for (int i = 0; i < 8; ++i) c1 += (kr[i] > thr) ? 1 : 0;
  c1 = bsum_i(c1, red, t);
  const int need = SEL - c1;
  int cut = 0;
  for (int bit = 12; bit >= 0; --bit) {
    int trial = cut | (1 << bit);
    int c = 0;
#pragma unroll
    for (int i = 0; i < 8; ++i) c += (kr[i] == thr && (t + i * 1024) < trial) ? 1 : 0;
    c = bsum_i(c, red, t);
    if (c < need) cut = trial;
  }

  float pm = 0.f;
#pragma unroll
  for (int i = 0; i < 8; ++i) pm = fmaxf(pm, pv[i]);
  pm = bmax_f(pm, redf, t);

  double ss = 0.0;
#pragma unroll
  for (int i = 0; i < 8; ++i) {
    int idx = t + i * 1024;
    bool sel = (kr[i] > thr) || (kr[i] == thr && idx <= cut);
    if (sel) ss += exp((double)pv[i] - (double)pm);
  }
  ss = bsum_d(ss, redd, t);

  if (t == 0) s_cnt = 0;
  __syncthreads();
  for (int i = 0; i < 8; ++i) {
    int idx = t + i * 1024;
    bool sel = (kr[i] > thr) || (kr[i] == thr && idx <= cut);
    if (sel) {
      int pos = atomicAdd(&s_cnt, 1);
      if (pos < SEL) {
        ib[e * SEL + pos] = idx;
        nws[e * SEL + pos] = (float)(exp((double)pv[i] - (double)pm) / ss);
        slot[(size_t)idx * N_E + e] = pos;
      }
    }
  }
}

// ---------------- expert GEMM ----------------
__global__ __launch_bounds__(256) void k_expert_gemm(const unsigned short* __restrict__ xb,
                                                     const unsigned short* __restrict__ web,
                                                     const float* __restrict__ be,
                                                     const int* __restrict__ ib,
                                                     const float* __restrict__ nws,
                                                     float* __restrict__ eo) {
  __shared__ unsigned short As[128 * 64];
  __shared__ unsigned short Bs[128 * 64];
  __shared__ int rowidx[128];
  __shared__ float nwss[128];
  const int e = blockIdx.z;
  const int bm = blockIdx.x * 128;
  const int bn = blockIdx.y * 128;
  const int t = threadIdx.x;
  const int wave = t >> 6, lane = t & 63;
  if (t < 128) {
    rowidx[t] = ib[e * SEL + bm + t];
    nwss[t] = nws[e * SEL + bm + t];
  }
  __syncthreads();
  const unsigned short* wbase = web + (size_t)e * D_IN * D_OUT;
  const int chunk = lane & 7;
  const unsigned short* aptr[4];
  const unsigned short* bptr[4];
  unsigned short* adst[4];
  unsigned short* bdst[4];
#pragma unroll
  for (int c = 0; c < 4; ++c) {
    int row = c * 32 + wave * 8 + (lane >> 3);
    aptr[c] = xb + (size_t)rowidx[row] * D_IN + chunk * 8;
    bptr[c] = wbase + (size_t)(bn + row) * D_IN + chunk * 8;
    adst[c] = As + row * 64 + chunk * 8;
    bdst[c] = Bs + row * 64 + chunk * 8;
  }
  floatx4 acc[4][4] = {};
  const int wm = wave >> 1, wn = wave & 1;
  const int fr = lane & 15, fq = lane >> 4;
  for (int k0 = 0; k0 < D_IN; k0 += 64) {
#pragma unroll
    for (int c = 0; c < 4; ++c) {
      async_cp16(aptr[c] + k0, adst[c]);
      async_cp16(bptr[c] + k0, bdst[c]);
    }
    __syncthreads();
#pragma unroll
    for (int kk = 0; kk < 2; ++kk) {
      bf16x8 af[4], bfr[4];
#pragma unroll
      for (int mt = 0; mt < 4; ++mt)
        af[mt] = *(const bf16x8*)(As + (wm * 64 + mt * 16 + fr) * 64 + kk * 32 + fq * 8);
#pragma unroll
      for (int nt = 0; nt < 4; ++nt)
        bfr[nt] = *(const bf16x8*)(Bs + (wn * 64 + nt * 16 + fr) * 64 + kk * 32 + fq * 8);
#pragma unroll
      for (int mt = 0; mt < 4; ++mt)
#pragma unroll
        for (int nt = 0; nt < 4; ++nt)
          acc[mt][nt] = __builtin_amdgcn_mfma_f32_16x16x32_bf16(af[mt], bfr[nt], acc[mt][nt], 0, 0, 0);
    }
    __syncthreads();
  }
  float bev[4];
#pragma unroll
  for (int nt = 0; nt < 4; ++nt) bev[nt] = be[e * D_OUT + bn + wn * 64 + nt * 16 + fr];
#pragma unroll
  for (int mt = 0; mt < 4; ++mt) {
#pragma unroll
    for (int r = 0; r < 4; ++r) {
      int lrow = wm * 64 + mt * 16 + fq * 4 + r;
      float nw = nwss[lrow];
      size_t rbase = ((size_t)e * SEL + bm + lrow) * D_OUT;
#pragma unroll
      for (int nt = 0; nt < 4; ++nt) {
        int cc = bn + wn * 64 + nt * 16 + fr;
        eo[rbase + cc] = (acc[mt][nt][r] + bev[nt]) * nw;
      }
    }
  }
}

// ---------------- combine ----------------
__global__ __launch_bounds__(256) void k_combine(const float* __restrict__ eo,
                                                 const int* __restrict__ slot,
                                                 float* __restrict__ out) {
  const int b = blockIdx.x;
  const int t = threadIdx.x;
  __shared__ int ss[8];
  if (t < 8) ss[t] = slot[(size_t)b * N_E + t];
  __syncthreads();
  const int d0 = t * 4;
  float vx[8], vy[8], vz[8], vw[8];
  float tx = 0.f, ty = 0.f, tz = 0.f, tw = 0.f;
#pragma unroll
  for (int e = 0; e < 8; ++e) {
    int k = ss[e];
    if (k >= 0) {
      float4 v = *(const float4*)(eo + ((size_t)e * SEL + k) * D_OUT + d0);
      vx[e] = v.x; vy[e] = v.y; vz[e] = v.z; vw[e] = v.w;
      tx += v.x; ty += v.y; tz += v.z; tw += v.w;
    } else {
      vx[e] = 0.f; vy[e] = 0.f; vz[e] = 0.f; vw[e] = 0.f;
    }
  }
#pragma unroll
  for (int e = 0; e < 8; ++e) {
    float4 o;
    o.x = tx + vx[e]; o.y = ty + vy[e]; o.z = tz + vz[e]; o.w = tw + vw[e];
    *(float4*)(out + (size_t)b * (N_E * D_OUT) + e * D_OUT + d0) = o;
  }
}

extern "C" void kernel_launch(void* const* d_in, const int* in_sizes, int n_in,
                              void* d_out, int out_size, void* d_ws, size_t ws_size,
                              hipStream_t stream) {
  const float* x  = (const float*)d_in[0];
  const float* w1 = (const float*)d_in[1];
  const float* b1 = (const float*)d_in[2];
  const float* wg = (const float*)d_in[3];
  const float* bg = (const float*)d_in[4];
  const float* w2 = (const float*)d_in[5];
  const float* b2 = (const float*)d_in[6];
  const float* we = (const float*)d_in[7];
  const float* be = (const float*)d_in[8];
  float* out = (float*)d_out;

  char* ws = (char*)d_ws;
  size_t off = 0;
  auto alloc = [&](size_t bytes) -> void* {
    void* p = ws + off;
    off += (bytes + 255) & ~(size_t)255;
    return p;
  };
  unsigned short* xb   = (unsigned short*)alloc((size_t)B_TOK * D_IN * 2);
  unsigned short* web  = (unsigned short*)alloc((size_t)N_E * D_IN * D_OUT * 2);
  unsigned short* wc   = (unsigned short*)alloc((size_t)256 * D_IN * 2);
  float* eo       = (float*)alloc((size_t)N_E * SEL * D_OUT * 4);
  float* ag       = (float*)alloc((size_t)B_TOK * 256 * 4);
  float* logits_f = (float*)alloc((size_t)B_TOK * N_E * 4);
  float* hc       = (float*)alloc((size_t)CAND_CAP * N_H * 4);
  float* p1       = (float*)alloc((size_t)8 * CAND_CAP * N_H * 4);
  float* pg       = (float*)alloc((size_t)8 * CAND_CAP * N_H * 4);
  int* ibuf       = (int*)alloc((size_t)N_E * SEL * 4);
  float* nws      = (float*)alloc((size_t)N_E * SEL * 4);
  int* slot       = (int*)alloc((size_t)B_TOK * N_E * 4);
  float* thrF     = (float*)alloc(8 * 4);
  int* clist      = (int*)alloc((size_t)CAND_CAP * 4);
  int* gcount     = (int*)alloc(4);
  if (off > ws_size) return;

  hipLaunchKernelGGL(k_cast_x, dim3(B_TOK * D_IN / (256 * 8)), dim3(256), 0, stream, x, xb);
  hipLaunchKernelGGL(k_cast_weT, dim3(16, 16, N_E), dim3(256), 0, stream, we, web);
  hipLaunchKernelGGL(k_cast_wr, dim3(16, 4), dim3(256), 0, stream, w1, wg, wc);
  hipLaunchKernelGGL(k_gemm_router, dim3(B_TOK / 128, 2), dim3(256), 0, stream, xb, wc, ag);
  hipLaunchKernelGGL(k_h_logits, dim3(B_TOK / 64), dim3(256), 0, stream, ag, b1, bg, w2, b2, logits_f);
  hipLaunchKernelGGL(k_pass1, dim3(N_E), dim3(1024), 0, stream, logits_f, thrF, gcount);
  hipLaunchKernelGGL(k_mark, dim3(B_TOK / 256), dim3(256), 0, stream, logits_f, thrF, slot, clist, gcount);
  hipLaunchKernelGGL(k_recheck_h_part, dim3(CAND_CAP / 32, 8), dim3(256), 0, stream,
                     x, w1, wg, clist, gcount, p1, pg);
  hipLaunchKernelGGL(k_recheck_gate, dim3(CAND_CAP * 32 / 256), dim3(256), 0, stream,
                     p1, pg, b1, bg, gcount, hc);
  hipLaunchKernelGGL(k_recheck_logits, dim3(64), dim3(256), 0, stream, hc, w2, b2, clist, gcount, logits_f);
  hipLaunchKernelGGL(k_final, dim3(N_E), dim3(1024), 0, stream, logits_f, ibuf, nws, slot);
  hipLaunchKernelGGL(k_expert_gemm, dim3(SEL / 128, D_OUT / 128, N_E), dim3(256), 0, stream,
                     xb, web, be, ibuf, nws, eo);
  hipLaunchKernelGGL(k_combine, dim3(B_TOK), dim3(256), 0, stream, eo, slot, out);
}